// Round 6
// baseline (118.019 us; speedup 1.0000x reference)
//
#include <hip/hip_runtime.h>
#include <hip/hip_bf16.h>

#define N_ATOMS 400000
#define BATCHES 64
#define DH 128

// Workspace float layout
#define ACC_OFF 0          // B*17 : [cnt, zsum[12], zsq[4]] per batch
#define ZC_OFF  1088       // B*12
#define RS_OFF  1856       // B*4
#define HB_OFF  2112       // B*128
#define UID_OFF 10304      // N_ATOMS bytes (as uint8), starts at float offset 10304

typedef float f4 __attribute__((ext_vector_type(4)));

__device__ __forceinline__ float silu_f(float x) { return x / (1.f + expf(-x)); }

// ---------------- Kernel 1: per-batch stats (cnt, Zsum, Zsqsum) + uid8 ----------------
// 512 atoms per block: each thread handles 2 atoms (strips at +0 and +256),
// accumulates locally, then ONE 16-value shuffle tree per distinct uid in the
// wave (sorted input -> almost always exactly 1 iteration).
__global__ __launch_bounds__(256) void k1_stats(
    const float* __restrict__ Z, const int* __restrict__ block_id,
    const int* __restrict__ batch_id, float* __restrict__ acc,
    unsigned char* __restrict__ uid8) {
  __shared__ float bins[BATCHES * 17];
  for (int i = threadIdx.x; i < BATCHES * 17; i += 256) bins[i] = 0.f;
  __syncthreads();

  const f4* Z4 = (const f4*)Z;
  int base = blockIdx.x * 512;
  int a0 = base + threadIdx.x;
  int a1 = a0 + 256;
  bool valid0 = (a0 < N_ATOMS);
  bool valid1 = (a1 < N_ATOMS);

  int u0 = -1, u1 = -1;
  float z0[12], z1[12];
#pragma unroll
  for (int j = 0; j < 12; ++j) { z0[j] = 0.f; z1[j] = 0.f; }

  if (valid0) {
    u0 = batch_id[block_id[a0]];
    uid8[a0] = (unsigned char)u0;
    f4 a = Z4[a0 * 3 + 0], b = Z4[a0 * 3 + 1], c = Z4[a0 * 3 + 2];
    z0[0] = a.x; z0[1] = a.y; z0[2]  = a.z; z0[3]  = a.w;
    z0[4] = b.x; z0[5] = b.y; z0[6]  = b.z; z0[7]  = b.w;
    z0[8] = c.x; z0[9] = c.y; z0[10] = c.z; z0[11] = c.w;
  }
  if (valid1) {
    u1 = batch_id[block_id[a1]];
    uid8[a1] = (unsigned char)u1;
    f4 a = Z4[a1 * 3 + 0], b = Z4[a1 * 3 + 1], c = Z4[a1 * 3 + 2];
    z1[0] = a.x; z1[1] = a.y; z1[2]  = a.z; z1[3]  = a.w;
    z1[4] = b.x; z1[5] = b.y; z1[6]  = b.z; z1[7]  = b.w;
    z1[8] = c.x; z1[9] = c.y; z1[10] = c.z; z1[11] = c.w;
  }

  // distinct-uid range present in this wave
  int lo = min(valid0 ? u0 : 0x7fffffff, valid1 ? u1 : 0x7fffffff);
  int hi = max(u0, u1);
#pragma unroll
  for (int m = 32; m; m >>= 1) {
    lo = min(lo, __shfl_xor(lo, m));
    hi = max(hi, __shfl_xor(hi, m));
  }

  if (hi >= 0) {
    for (int u = lo; u <= hi; ++u) {
      bool m0 = valid0 && (u0 == u);
      bool m1 = valid1 && (u1 == u);
      unsigned long long b0 = __ballot(m0);
      unsigned long long b1 = __ballot(m1);
      float vals[16];
#pragma unroll
      for (int j = 0; j < 12; ++j)
        vals[j] = (m0 ? z0[j] : 0.f) + (m1 ? z1[j] : 0.f);
#pragma unroll
      for (int c = 0; c < 4; ++c) {
        float s0 = z0[c*3]*z0[c*3] + z0[c*3+1]*z0[c*3+1] + z0[c*3+2]*z0[c*3+2];
        float s1 = z1[c*3]*z1[c*3] + z1[c*3+1]*z1[c*3+1] + z1[c*3+2]*z1[c*3+2];
        vals[12 + c] = (m0 ? s0 : 0.f) + (m1 ? s1 : 0.f);
      }
#pragma unroll
      for (int v = 0; v < 16; ++v) {
        float x = vals[v];
#pragma unroll
        for (int m = 32; m; m >>= 1) x += __shfl_xor(x, m);
        vals[v] = x;
      }
      if ((threadIdx.x & 63) == 0) {
        atomicAdd(&bins[u * 17 + 0], (float)(__popcll(b0) + __popcll(b1)));
#pragma unroll
        for (int v = 0; v < 16; ++v) atomicAdd(&bins[u * 17 + 1 + v], vals[v]);
      }
    }
  }
  __syncthreads();
  for (int i = threadIdx.x; i < BATCHES * 17; i += 256) {
    float v = bins[i];
    if (v != 0.f) atomicAdd(&acc[i], v);
  }
}

// ---------------- Kernel 2: rescale + RBF + 2-layer MLP (per batch row) ----------------
__global__ __launch_bounds__(128) void k2_mlp(
    const float* __restrict__ sigma, const float* __restrict__ W1,
    const float* __restrict__ b1, const float* __restrict__ W2,
    const float* __restrict__ b2, const float* __restrict__ acc,
    float* __restrict__ Zc, float* __restrict__ resc,
    float* __restrict__ hbuf, float* __restrict__ resc_out) {
  int b = blockIdx.x, t = threadIdx.x;
  __shared__ float rbf_s[64];
  __shared__ float h1_s[128];
  __shared__ float resc_s[4];

  if (t < 4) {
    int c = t;
    float cnt = acc[b * 17];
    float cs = fmaxf(cnt, 1.f);
    float s2 = 0.f;
#pragma unroll
    for (int a = 0; a < 3; ++a) {
      float zc = acc[b * 17 + 1 + c * 3 + a] / cs;
      Zc[b * 12 + c * 3 + a] = zc;
      s2 += zc * zc;
    }
    float sq = acc[b * 17 + 13 + c] - cnt * s2;
    float denom = fmaxf(cnt * 3.f - 1.f, 1.f);
    float var = fmaxf(sq / denom, 0.f);
    float r = sigma[c] / sqrtf(var);
    resc_s[c] = r;
    resc[b * 4 + c] = r;
    resc_out[b * 4 + c] = r;
  }
  __syncthreads();
  if (t < 64) {
    int c = t >> 4, ri = t & 15;
    float ds = resc_s[c] * (1.f / 7.f);
    float env = 0.f;
    if (ds < 1.f) {
      float d2 = ds * ds;
      float d5 = d2 * d2 * ds;
      env = 1.f - 21.f * d5 + 35.f * d5 * ds - 15.f * d5 * d2;
    }
    float off = (float)ri * (1.f / 15.f);
    float dd = ds - off;
    rbf_s[t] = env * expf(-112.5f * dd * dd);
  }
  __syncthreads();
  float s = b1[t];
#pragma unroll 8
  for (int k = 0; k < 64; ++k) s += rbf_s[k] * W1[k * 128 + t];
  h1_s[t] = silu_f(s);
  __syncthreads();
  float s2 = b2[t];
#pragma unroll 8
  for (int k = 0; k < 128; ++k) s2 += h1_s[k] * W2[k * 128 + t];
  hbuf[b * 128 + t] = silu_f(s2);
}

// ---------------- Kernel 3: per-atom apply (Z out + H add + LayerNorm) ----------------
// 256 threads = 16 subgroups of 16 lanes; each subgroup handles 4 atoms
// (lane owns two f4 quarters of each 128-float row). 64 atoms per block.
__global__ __launch_bounds__(256) void k3_apply(
    const float* __restrict__ H, const float* __restrict__ Z,
    const unsigned char* __restrict__ uid8,
    const float* __restrict__ ln_w, const float* __restrict__ ln_b,
    const float* __restrict__ Zc, const float* __restrict__ resc,
    const float* __restrict__ hbuf,
    float* __restrict__ Hout, float* __restrict__ Zout) {
  int t = threadIdx.x;
  int sub = t >> 4, l = t & 15;
  int base = blockIdx.x * 64;
  int n0 = base + sub * 4;

  unsigned int u4 = *(const unsigned int*)&uid8[n0];
  int uid[4] = {(int)(u4 & 0xff), (int)((u4 >> 8) & 0xff),
                (int)((u4 >> 16) & 0xff), (int)(u4 >> 24)};

  const f4* H4 = (const f4*)H;
  const f4* HB4 = (const f4*)hbuf;

  f4 va[4], vb[4];
#pragma unroll
  for (int a = 0; a < 4; ++a) {
    size_t r = (size_t)(n0 + a) * 32;
    va[a] = H4[r + l];
    vb[a] = H4[r + 16 + l];
  }
  f4 xa[4], xb[4];
#pragma unroll
  for (int a = 0; a < 4; ++a) {
    xa[a] = va[a] + HB4[uid[a] * 32 + l];
    xb[a] = vb[a] + HB4[uid[a] * 32 + 16 + l];
  }

  float s[4], q[4];
#pragma unroll
  for (int a = 0; a < 4; ++a) {
    s[a] = (xa[a].x + xa[a].y + xa[a].z + xa[a].w)
         + (xb[a].x + xb[a].y + xb[a].z + xb[a].w);
    q[a] = (xa[a].x*xa[a].x + xa[a].y*xa[a].y + xa[a].z*xa[a].z + xa[a].w*xa[a].w)
         + (xb[a].x*xb[a].x + xb[a].y*xb[a].y + xb[a].z*xb[a].z + xb[a].w*xb[a].w);
  }
#pragma unroll
  for (int m = 1; m < 16; m <<= 1) {
#pragma unroll
    for (int a = 0; a < 4; ++a) {
      s[a] += __shfl_xor(s[a], m);
      q[a] += __shfl_xor(q[a], m);
    }
  }

  const f4* LW4 = (const f4*)ln_w;
  const f4* LB4 = (const f4*)ln_b;
  f4 w0 = LW4[l], w1 = LW4[16 + l];
  f4 bb0 = LB4[l], bb1 = LB4[16 + l];

  f4* HO4 = (f4*)Hout;
#pragma unroll
  for (int a = 0; a < 4; ++a) {
    float mean = s[a] * (1.f / 128.f);
    float inv = rsqrtf(q[a] * (1.f / 128.f) - mean * mean + 1e-5f);
    size_t r = (size_t)(n0 + a) * 32;
    f4 o;
    o.x = (xa[a].x - mean) * inv * w0.x + bb0.x;
    o.y = (xa[a].y - mean) * inv * w0.y + bb0.y;
    o.z = (xa[a].z - mean) * inv * w0.z + bb0.z;
    o.w = (xa[a].w - mean) * inv * w0.w + bb0.w;
    HO4[r + l] = o;
    o.x = (xb[a].x - mean) * inv * w1.x + bb1.x;
    o.y = (xb[a].y - mean) * inv * w1.y + bb1.y;
    o.z = (xb[a].z - mean) * inv * w1.z + bb1.z;
    o.w = (xb[a].w - mean) * inv * w1.w + bb1.w;
    HO4[r + 16 + l] = o;
  }

  // Z path: threads 0..191 each handle one f4 row (atom = base + t/3, comp = t%3)
  if (t < 192) {
    int atom = base + t / 3;
    int comp = t - (t / 3) * 3;
    int zuid = uid8[atom];
    const f4* Z4 = (const f4*)Z;
    f4 z = Z4[atom * 3 + comp];
    float zz[4] = {z.x, z.y, z.z, z.w};
    float oo[4];
#pragma unroll
    for (int k = 0; k < 4; ++k) {
      int j = comp * 4 + k;
      int c = j / 3;
      float zcv = Zc[zuid * 12 + j];
      float r = resc[zuid * 4 + c];
      oo[k] = zcv + (zz[k] - zcv) * r;
    }
    f4 ov = {oo[0], oo[1], oo[2], oo[3]};
    ((f4*)Zout)[atom * 3 + comp] = ov;
  }
}

extern "C" void kernel_launch(void* const* d_in, const int* in_sizes, int n_in,
                              void* d_out, int out_size, void* d_ws, size_t ws_size,
                              hipStream_t stream) {
  const float* H     = (const float*)d_in[0];
  const float* Z     = (const float*)d_in[1];
  const float* sigma = (const float*)d_in[2];
  const float* W1    = (const float*)d_in[3];
  const float* b1    = (const float*)d_in[4];
  const float* W2    = (const float*)d_in[5];
  const float* b2    = (const float*)d_in[6];
  const float* ln_w  = (const float*)d_in[7];
  const float* ln_b  = (const float*)d_in[8];
  const int* block_id = (const int*)d_in[9];
  const int* batch_id = (const int*)d_in[10];

  float* ws   = (float*)d_ws;
  float* acc  = ws + ACC_OFF;
  float* Zc   = ws + ZC_OFF;
  float* resc = ws + RS_OFF;
  float* hbuf = ws + HB_OFF;
  unsigned char* uid8 = (unsigned char*)(ws + UID_OFF);

  float* Hout = (float*)d_out;
  float* Zout = Hout + (size_t)N_ATOMS * DH;
  float* resc_out = Zout + (size_t)N_ATOMS * 12;

  hipMemsetAsync(acc, 0, BATCHES * 17 * sizeof(float), stream);
  k1_stats<<<(N_ATOMS + 511) / 512, 256, 0, stream>>>(Z, block_id, batch_id, acc, uid8);
  k2_mlp<<<BATCHES, 128, 0, stream>>>(sigma, W1, b1, W2, b2, acc, Zc, resc, hbuf, resc_out);
  k3_apply<<<N_ATOMS / 64, 256, 0, stream>>>(H, Z, uid8, ln_w, ln_b,
                                             Zc, resc, hbuf, Hout, Zout);
}

// Round 7
// 108.204 us; speedup vs baseline: 1.0907x; 1.0907x over previous
//
#include <hip/hip_runtime.h>
#include <hip/hip_bf16.h>

#define N_ATOMS 400000
#define BATCHES 64
#define DH 128
#define NB1 782            // ceil(400000/512) k1 blocks

// Workspace float layout
#define PART_OFF 0         // NB1*34 floats: per-block partials [lo 17][hi 17]
#define HDR_OFF  26588     // NB1*2 ints: {lo, hi or -1}
#define ZC_OFF   28160     // B*12
#define RS_OFF   28928     // B*4
#define HB_OFF   29184     // B*128
#define UID_OFF  37376     // N_ATOMS bytes (uint8)

typedef float f4 __attribute__((ext_vector_type(4)));

__device__ __forceinline__ f4 ntload4(const f4* p) { return __builtin_nontemporal_load(p); }
__device__ __forceinline__ float silu_f(float x) { return x / (1.f + expf(-x)); }

// ---------------- Kernel 1: per-batch stats -> compact per-block partials ----------------
// 512 threads, 1 atom each (R5's proven wave structure). LDS bins + compact flush.
__global__ __launch_bounds__(512) void k1_stats(
    const float* __restrict__ Z, const int* __restrict__ block_id,
    const int* __restrict__ batch_id, float* __restrict__ partials,
    int* __restrict__ hdr, unsigned char* __restrict__ uid8) {
  __shared__ float bins[BATCHES * 17];
  __shared__ int smin, smax;
  for (int i = threadIdx.x; i < BATCHES * 17; i += 512) bins[i] = 0.f;
  if (threadIdx.x == 0) { smin = 1 << 30; smax = -1; }
  __syncthreads();

  const f4* Z4 = (const f4*)Z;
  int n = blockIdx.x * 512 + threadIdx.x;
  bool valid = (n < N_ATOMS);
  int uid = -1;
  float z[12];
#pragma unroll
  for (int j = 0; j < 12; ++j) z[j] = 0.f;
  if (valid) {
    uid = batch_id[block_id[n]];
    uid8[n] = (unsigned char)uid;
    f4 a = Z4[n * 3 + 0];
    f4 b = Z4[n * 3 + 1];
    f4 c = Z4[n * 3 + 2];
    z[0] = a.x; z[1] = a.y; z[2]  = a.z; z[3]  = a.w;
    z[4] = b.x; z[5] = b.y; z[6]  = b.z; z[7]  = b.w;
    z[8] = c.x; z[9] = c.y; z[10] = c.z; z[11] = c.w;
  }

  int lo = valid ? uid : 0x7fffffff;
  int hi = uid;
#pragma unroll
  for (int m = 32; m; m >>= 1) {
    lo = min(lo, __shfl_xor(lo, m));
    hi = max(hi, __shfl_xor(hi, m));
  }

  if (lo == hi) {
    // wave-uniform uid (common case: sorted input)
    float vals[16];
#pragma unroll
    for (int j = 0; j < 12; ++j) vals[j] = z[j];
#pragma unroll
    for (int c = 0; c < 4; ++c)
      vals[12 + c] = z[c*3]*z[c*3] + z[c*3+1]*z[c*3+1] + z[c*3+2]*z[c*3+2];
#pragma unroll
    for (int v = 0; v < 16; ++v) {
      float x = vals[v];
#pragma unroll
      for (int m = 32; m; m >>= 1) x += __shfl_xor(x, m);
      vals[v] = x;
    }
    unsigned long long mb = __ballot(valid);
    if ((threadIdx.x & 63) == 0) {
      atomicAdd(&bins[hi * 17 + 0], (float)__popcll(mb));
#pragma unroll
      for (int v = 0; v < 16; ++v) atomicAdd(&bins[hi * 17 + 1 + v], vals[v]);
    }
  } else if (hi >= 0) {
    // rare: wave straddles a batch boundary -> per-lane LDS atomics
    if (valid) {
      atomicAdd(&bins[uid * 17 + 0], 1.f);
#pragma unroll
      for (int j = 0; j < 12; ++j) atomicAdd(&bins[uid * 17 + 1 + j], z[j]);
#pragma unroll
      for (int c = 0; c < 4; ++c)
        atomicAdd(&bins[uid * 17 + 13 + c],
                  z[c*3]*z[c*3] + z[c*3+1]*z[c*3+1] + z[c*3+2]*z[c*3+2]);
    }
  }
  if ((threadIdx.x & 63) == 0 && hi >= 0) {
    atomicMin(&smin, lo);
    atomicMax(&smax, hi);
  }
  __syncthreads();

  // compact flush: a 512-atom window spans at most 2 batches (min batch ~5700)
  int blo = smin, bhi = smax;
  if (threadIdx.x < 17) {
    partials[blockIdx.x * 34 + threadIdx.x] = bins[blo * 17 + threadIdx.x];
  } else if (threadIdx.x < 34) {
    int i = threadIdx.x - 17;
    partials[blockIdx.x * 34 + threadIdx.x] = (bhi > blo) ? bins[bhi * 17 + i] : 0.f;
  } else if (threadIdx.x == 34) {
    hdr[blockIdx.x * 2 + 0] = blo;
    hdr[blockIdx.x * 2 + 1] = (bhi > blo) ? bhi : -1;
  }
}

// ---------------- Kernel 2: gather partials + rescale + RBF + MLP (per batch) ----------------
__global__ __launch_bounds__(128) void k2_mlp(
    const float* __restrict__ sigma, const float* __restrict__ W1,
    const float* __restrict__ b1, const float* __restrict__ W2,
    const float* __restrict__ b2,
    const float* __restrict__ partials, const int* __restrict__ hdr,
    float* __restrict__ Zc, float* __restrict__ resc,
    float* __restrict__ hbuf, float* __restrict__ resc_out) {
  int b = blockIdx.x, t = threadIdx.x;
  __shared__ float sbins[17];
  __shared__ float rbf_s[64];
  __shared__ float h1_s[128];
  __shared__ float resc_s[4];

  if (t < 17) sbins[t] = 0.f;
  __syncthreads();

  // reduce matching per-block partial records (~12-14 per batch)
  {
    float local[17];
#pragma unroll
    for (int i = 0; i < 17; ++i) local[i] = 0.f;
    bool touched = false;
    for (int r = t; r < NB1; r += 128) {
      int lo = hdr[r * 2], hi = hdr[r * 2 + 1];
      if (lo == b) {
        touched = true;
#pragma unroll
        for (int i = 0; i < 17; ++i) local[i] += partials[r * 34 + i];
      }
      if (hi == b) {
        touched = true;
#pragma unroll
        for (int i = 0; i < 17; ++i) local[i] += partials[r * 34 + 17 + i];
      }
    }
    if (touched) {
#pragma unroll
      for (int i = 0; i < 17; ++i) atomicAdd(&sbins[i], local[i]);
    }
  }
  __syncthreads();

  if (t < 4) {
    int c = t;
    float cnt = sbins[0];
    float cs = fmaxf(cnt, 1.f);
    float s2 = 0.f;
#pragma unroll
    for (int a = 0; a < 3; ++a) {
      float zc = sbins[1 + c * 3 + a] / cs;
      Zc[b * 12 + c * 3 + a] = zc;
      s2 += zc * zc;
    }
    float sq = sbins[13 + c] - cnt * s2;
    float denom = fmaxf(cnt * 3.f - 1.f, 1.f);
    float var = fmaxf(sq / denom, 0.f);
    float r = sigma[c] / sqrtf(var);
    resc_s[c] = r;
    resc[b * 4 + c] = r;
    resc_out[b * 4 + c] = r;
  }
  __syncthreads();
  if (t < 64) {
    int c = t >> 4, ri = t & 15;
    float ds = resc_s[c] * (1.f / 7.f);
    float env = 0.f;
    if (ds < 1.f) {
      float d2 = ds * ds;
      float d5 = d2 * d2 * ds;
      env = 1.f - 21.f * d5 + 35.f * d5 * ds - 15.f * d5 * d2;
    }
    float off = (float)ri * (1.f / 15.f);
    float dd = ds - off;
    rbf_s[t] = env * expf(-112.5f * dd * dd);
  }
  __syncthreads();
  float s = b1[t];
#pragma unroll 8
  for (int k = 0; k < 64; ++k) s += rbf_s[k] * W1[k * 128 + t];
  h1_s[t] = silu_f(s);
  __syncthreads();
  float s2 = b2[t];
#pragma unroll 8
  for (int k = 0; k < 128; ++k) s2 += h1_s[k] * W2[k * 128 + t];
  hbuf[b * 128 + t] = silu_f(s2);
}

// ---------------- Kernel 3: per-atom apply (identical to round-5 best) ----------------
__global__ __launch_bounds__(256) void k3_apply(
    const float* __restrict__ H, const float* __restrict__ Z,
    const unsigned char* __restrict__ uid8,
    const float* __restrict__ ln_w, const float* __restrict__ ln_b,
    const float* __restrict__ Zc, const float* __restrict__ resc,
    const float* __restrict__ hbuf,
    float* __restrict__ Hout, float* __restrict__ Zout) {
  int t = threadIdx.x;
  int sub = t >> 4, l = t & 15;
  int base = blockIdx.x * 64;
  int n0 = base + sub * 4;

  unsigned int u4 = *(const unsigned int*)&uid8[n0];
  int uid[4] = {(int)(u4 & 0xff), (int)((u4 >> 8) & 0xff),
                (int)((u4 >> 16) & 0xff), (int)(u4 >> 24)};

  const f4* H4 = (const f4*)H;
  const f4* HB4 = (const f4*)hbuf;

  f4 va[4], vb[4];
#pragma unroll
  for (int a = 0; a < 4; ++a) {
    size_t r = (size_t)(n0 + a) * 32;
    va[a] = ntload4(&H4[r + l]);
    vb[a] = ntload4(&H4[r + 16 + l]);
  }
  f4 xa[4], xb[4];
#pragma unroll
  for (int a = 0; a < 4; ++a) {
    xa[a] = va[a] + HB4[uid[a] * 32 + l];
    xb[a] = vb[a] + HB4[uid[a] * 32 + 16 + l];
  }

  float s[4], q[4];
#pragma unroll
  for (int a = 0; a < 4; ++a) {
    s[a] = (xa[a].x + xa[a].y + xa[a].z + xa[a].w)
         + (xb[a].x + xb[a].y + xb[a].z + xb[a].w);
    q[a] = (xa[a].x*xa[a].x + xa[a].y*xa[a].y + xa[a].z*xa[a].z + xa[a].w*xa[a].w)
         + (xb[a].x*xb[a].x + xb[a].y*xb[a].y + xb[a].z*xb[a].z + xb[a].w*xb[a].w);
  }
#pragma unroll
  for (int m = 1; m < 16; m <<= 1) {
#pragma unroll
    for (int a = 0; a < 4; ++a) {
      s[a] += __shfl_xor(s[a], m);
      q[a] += __shfl_xor(q[a], m);
    }
  }

  const f4* LW4 = (const f4*)ln_w;
  const f4* LB4 = (const f4*)ln_b;
  f4 w0 = LW4[l], w1 = LW4[16 + l];
  f4 bb0 = LB4[l], bb1 = LB4[16 + l];

  f4* HO4 = (f4*)Hout;
#pragma unroll
  for (int a = 0; a < 4; ++a) {
    float mean = s[a] * (1.f / 128.f);
    float inv = rsqrtf(q[a] * (1.f / 128.f) - mean * mean + 1e-5f);
    size_t r = (size_t)(n0 + a) * 32;
    f4 o;
    o.x = (xa[a].x - mean) * inv * w0.x + bb0.x;
    o.y = (xa[a].y - mean) * inv * w0.y + bb0.y;
    o.z = (xa[a].z - mean) * inv * w0.z + bb0.z;
    o.w = (xa[a].w - mean) * inv * w0.w + bb0.w;
    HO4[r + l] = o;
    o.x = (xb[a].x - mean) * inv * w1.x + bb1.x;
    o.y = (xb[a].y - mean) * inv * w1.y + bb1.y;
    o.z = (xb[a].z - mean) * inv * w1.z + bb1.z;
    o.w = (xb[a].w - mean) * inv * w1.w + bb1.w;
    HO4[r + 16 + l] = o;
  }

  // Z path: threads 0..191 each handle one f4 row (atom = base + t/3, comp = t%3)
  if (t < 192) {
    int atom = base + t / 3;
    int comp = t - (t / 3) * 3;
    int zuid = uid8[atom];
    const f4* Z4 = (const f4*)Z;
    f4 z = Z4[atom * 3 + comp];
    float zz[4] = {z.x, z.y, z.z, z.w};
    float oo[4];
#pragma unroll
    for (int k = 0; k < 4; ++k) {
      int j = comp * 4 + k;
      int c = j / 3;
      float zcv = Zc[zuid * 12 + j];
      float r = resc[zuid * 4 + c];
      oo[k] = zcv + (zz[k] - zcv) * r;
    }
    f4 ov = {oo[0], oo[1], oo[2], oo[3]};
    ((f4*)Zout)[atom * 3 + comp] = ov;
  }
}

extern "C" void kernel_launch(void* const* d_in, const int* in_sizes, int n_in,
                              void* d_out, int out_size, void* d_ws, size_t ws_size,
                              hipStream_t stream) {
  const float* H     = (const float*)d_in[0];
  const float* Z     = (const float*)d_in[1];
  const float* sigma = (const float*)d_in[2];
  const float* W1    = (const float*)d_in[3];
  const float* b1    = (const float*)d_in[4];
  const float* W2    = (const float*)d_in[5];
  const float* b2    = (const float*)d_in[6];
  const float* ln_w  = (const float*)d_in[7];
  const float* ln_b  = (const float*)d_in[8];
  const int* block_id = (const int*)d_in[9];
  const int* batch_id = (const int*)d_in[10];

  float* ws       = (float*)d_ws;
  float* partials = ws + PART_OFF;
  int*   hdr      = (int*)(ws + HDR_OFF);
  float* Zc       = ws + ZC_OFF;
  float* resc     = ws + RS_OFF;
  float* hbuf     = ws + HB_OFF;
  unsigned char* uid8 = (unsigned char*)(ws + UID_OFF);

  float* Hout = (float*)d_out;
  float* Zout = Hout + (size_t)N_ATOMS * DH;
  float* resc_out = Zout + (size_t)N_ATOMS * 12;

  k1_stats<<<NB1, 512, 0, stream>>>(Z, block_id, batch_id, partials, hdr, uid8);
  k2_mlp<<<BATCHES, 128, 0, stream>>>(sigma, W1, b1, W2, b2, partials, hdr,
                                      Zc, resc, hbuf, resc_out);
  k3_apply<<<N_ATOMS / 64, 256, 0, stream>>>(H, Z, uid8, ln_w, ln_b,
                                             Zc, resc, hbuf, Hout, Zout);
}

// Round 8
// 103.261 us; speedup vs baseline: 1.1429x; 1.0479x over previous
//
#include <hip/hip_runtime.h>
#include <hip/hip_bf16.h>

#define N_ATOMS 400000
#define BATCHES 64
#define DH 128

// Workspace float layout
#define ACC_OFF 0          // B*17 : [cnt, zsum[12], zsq[4]] per batch
#define ZC_OFF  1088       // B*12
#define RS_OFF  1856       // B*4
#define HB_OFF  2112       // B*128
#define UID_OFF 10304      // N_ATOMS bytes (as uint8), starts at float offset 10304

typedef float f4 __attribute__((ext_vector_type(4)));

__device__ __forceinline__ f4 ntload4(const f4* p) { return __builtin_nontemporal_load(p); }
__device__ __forceinline__ float silu_f(float x) { return x / (1.f + expf(-x)); }

// ---------------- Kernel 1: per-batch stats (cnt, Zsum, Zsqsum) + uid8 ----------------
__global__ __launch_bounds__(256) void k1_stats(
    const float* __restrict__ Z, const int* __restrict__ block_id,
    const int* __restrict__ batch_id, float* __restrict__ acc,
    unsigned char* __restrict__ uid8) {
  __shared__ float bins[BATCHES * 17];
  for (int i = threadIdx.x; i < BATCHES * 17; i += 256) bins[i] = 0.f;
  __syncthreads();

  const f4* Z4 = (const f4*)Z;
  int n = blockIdx.x * 256 + threadIdx.x;
  bool valid = (n < N_ATOMS);
  int uid = -1;
  float z[12];
#pragma unroll
  for (int j = 0; j < 12; ++j) z[j] = 0.f;
  if (valid) {
    uid = batch_id[block_id[n]];
    uid8[n] = (unsigned char)uid;
    f4 a = Z4[n * 3 + 0];
    f4 b = Z4[n * 3 + 1];
    f4 c = Z4[n * 3 + 2];
    z[0] = a.x; z[1] = a.y; z[2]  = a.z; z[3]  = a.w;
    z[4] = b.x; z[5] = b.y; z[6]  = b.z; z[7]  = b.w;
    z[8] = c.x; z[9] = c.y; z[10] = c.z; z[11] = c.w;
  }

  int lo = valid ? uid : 0x7fffffff;
  int hi = uid;
#pragma unroll
  for (int m = 32; m; m >>= 1) {
    lo = min(lo, __shfl_xor(lo, m));
    hi = max(hi, __shfl_xor(hi, m));
  }

  if (lo == hi) {
    // wave-uniform uid (common case: sorted input)
    float vals[16];
#pragma unroll
    for (int j = 0; j < 12; ++j) vals[j] = z[j];
#pragma unroll
    for (int c = 0; c < 4; ++c)
      vals[12 + c] = z[c*3]*z[c*3] + z[c*3+1]*z[c*3+1] + z[c*3+2]*z[c*3+2];
#pragma unroll
    for (int v = 0; v < 16; ++v) {
      float x = vals[v];
#pragma unroll
      for (int m = 32; m; m >>= 1) x += __shfl_xor(x, m);
      vals[v] = x;
    }
    unsigned long long mb = __ballot(valid);
    if ((threadIdx.x & 63) == 0) {
      atomicAdd(&bins[hi * 17 + 0], (float)__popcll(mb));
#pragma unroll
      for (int v = 0; v < 16; ++v) atomicAdd(&bins[hi * 17 + 1 + v], vals[v]);
    }
  } else if (hi >= 0) {
    // rare: wave straddles a batch boundary -> per-lane LDS atomics
    if (valid) {
      atomicAdd(&bins[uid * 17 + 0], 1.f);
#pragma unroll
      for (int j = 0; j < 12; ++j) atomicAdd(&bins[uid * 17 + 1 + j], z[j]);
#pragma unroll
      for (int c = 0; c < 4; ++c)
        atomicAdd(&bins[uid * 17 + 13 + c],
                  z[c*3]*z[c*3] + z[c*3+1]*z[c*3+1] + z[c*3+2]*z[c*3+2]);
    }
  }
  __syncthreads();
  for (int i = threadIdx.x; i < BATCHES * 17; i += 256) {
    float v = bins[i];
    if (v != 0.f) atomicAdd(&acc[i], v);
  }
}

// ---------------- Kernel 2: rescale + RBF + 2-layer MLP (per batch row) ----------------
__global__ __launch_bounds__(128) void k2_mlp(
    const float* __restrict__ sigma, const float* __restrict__ W1,
    const float* __restrict__ b1, const float* __restrict__ W2,
    const float* __restrict__ b2, const float* __restrict__ acc,
    float* __restrict__ Zc, float* __restrict__ resc,
    float* __restrict__ hbuf, float* __restrict__ resc_out) {
  int b = blockIdx.x, t = threadIdx.x;
  __shared__ float rbf_s[64];
  __shared__ float h1_s[128];
  __shared__ float resc_s[4];

  if (t < 4) {
    int c = t;
    float cnt = acc[b * 17];
    float cs = fmaxf(cnt, 1.f);
    float s2 = 0.f;
#pragma unroll
    for (int a = 0; a < 3; ++a) {
      float zc = acc[b * 17 + 1 + c * 3 + a] / cs;
      Zc[b * 12 + c * 3 + a] = zc;
      s2 += zc * zc;
    }
    float sq = acc[b * 17 + 13 + c] - cnt * s2;
    float denom = fmaxf(cnt * 3.f - 1.f, 1.f);
    float var = fmaxf(sq / denom, 0.f);
    float r = sigma[c] / sqrtf(var);
    resc_s[c] = r;
    resc[b * 4 + c] = r;
    resc_out[b * 4 + c] = r;
  }
  __syncthreads();
  if (t < 64) {
    int c = t >> 4, ri = t & 15;
    float ds = resc_s[c] * (1.f / 7.f);
    float env = 0.f;
    if (ds < 1.f) {
      float d2 = ds * ds;
      float d5 = d2 * d2 * ds;
      env = 1.f - 21.f * d5 + 35.f * d5 * ds - 15.f * d5 * d2;
    }
    float off = (float)ri * (1.f / 15.f);
    float dd = ds - off;
    rbf_s[t] = env * expf(-112.5f * dd * dd);
  }
  __syncthreads();
  float s = b1[t];
#pragma unroll 8
  for (int k = 0; k < 64; ++k) s += rbf_s[k] * W1[k * 128 + t];
  h1_s[t] = silu_f(s);
  __syncthreads();
  float s2 = b2[t];
#pragma unroll 8
  for (int k = 0; k < 128; ++k) s2 += h1_s[k] * W2[k * 128 + t];
  hbuf[b * 128 + t] = silu_f(s2);
}

// ---------------- Kernel 3: per-atom apply (Z out + H add + LayerNorm) ----------------
// 256 threads = 16 subgroups of 16 lanes; each subgroup handles 4 atoms
// (lane owns two f4 quarters of each 128-float row). 64 atoms per block.
__global__ __launch_bounds__(256) void k3_apply(
    const float* __restrict__ H, const float* __restrict__ Z,
    const unsigned char* __restrict__ uid8,
    const float* __restrict__ ln_w, const float* __restrict__ ln_b,
    const float* __restrict__ Zc, const float* __restrict__ resc,
    const float* __restrict__ hbuf,
    float* __restrict__ Hout, float* __restrict__ Zout) {
  int t = threadIdx.x;
  int sub = t >> 4, l = t & 15;
  int base = blockIdx.x * 64;
  int n0 = base + sub * 4;

  unsigned int u4 = *(const unsigned int*)&uid8[n0];
  int uid[4] = {(int)(u4 & 0xff), (int)((u4 >> 8) & 0xff),
                (int)((u4 >> 16) & 0xff), (int)(u4 >> 24)};

  const f4* H4 = (const f4*)H;
  const f4* HB4 = (const f4*)hbuf;

  f4 va[4], vb[4];
#pragma unroll
  for (int a = 0; a < 4; ++a) {
    size_t r = (size_t)(n0 + a) * 32;
    va[a] = ntload4(&H4[r + l]);
    vb[a] = ntload4(&H4[r + 16 + l]);
  }
  f4 xa[4], xb[4];
#pragma unroll
  for (int a = 0; a < 4; ++a) {
    xa[a] = va[a] + HB4[uid[a] * 32 + l];
    xb[a] = vb[a] + HB4[uid[a] * 32 + 16 + l];
  }

  float s[4], q[4];
#pragma unroll
  for (int a = 0; a < 4; ++a) {
    s[a] = (xa[a].x + xa[a].y + xa[a].z + xa[a].w)
         + (xb[a].x + xb[a].y + xb[a].z + xb[a].w);
    q[a] = (xa[a].x*xa[a].x + xa[a].y*xa[a].y + xa[a].z*xa[a].z + xa[a].w*xa[a].w)
         + (xb[a].x*xb[a].x + xb[a].y*xb[a].y + xb[a].z*xb[a].z + xb[a].w*xb[a].w);
  }
#pragma unroll
  for (int m = 1; m < 16; m <<= 1) {
#pragma unroll
    for (int a = 0; a < 4; ++a) {
      s[a] += __shfl_xor(s[a], m);
      q[a] += __shfl_xor(q[a], m);
    }
  }

  const f4* LW4 = (const f4*)ln_w;
  const f4* LB4 = (const f4*)ln_b;
  f4 w0 = LW4[l], w1 = LW4[16 + l];
  f4 bb0 = LB4[l], bb1 = LB4[16 + l];

  f4* HO4 = (f4*)Hout;
#pragma unroll
  for (int a = 0; a < 4; ++a) {
    float mean = s[a] * (1.f / 128.f);
    float inv = rsqrtf(q[a] * (1.f / 128.f) - mean * mean + 1e-5f);
    size_t r = (size_t)(n0 + a) * 32;
    f4 o;
    o.x = (xa[a].x - mean) * inv * w0.x + bb0.x;
    o.y = (xa[a].y - mean) * inv * w0.y + bb0.y;
    o.z = (xa[a].z - mean) * inv * w0.z + bb0.z;
    o.w = (xa[a].w - mean) * inv * w0.w + bb0.w;
    HO4[r + l] = o;
    o.x = (xb[a].x - mean) * inv * w1.x + bb1.x;
    o.y = (xb[a].y - mean) * inv * w1.y + bb1.y;
    o.z = (xb[a].z - mean) * inv * w1.z + bb1.z;
    o.w = (xb[a].w - mean) * inv * w1.w + bb1.w;
    HO4[r + 16 + l] = o;
  }

  // Z path: threads 0..191 each handle one f4 row (atom = base + t/3, comp = t%3)
  if (t < 192) {
    int atom = base + t / 3;
    int comp = t - (t / 3) * 3;
    int zuid = uid8[atom];
    const f4* Z4 = (const f4*)Z;
    f4 z = Z4[atom * 3 + comp];
    float zz[4] = {z.x, z.y, z.z, z.w};
    float oo[4];
#pragma unroll
    for (int k = 0; k < 4; ++k) {
      int j = comp * 4 + k;
      int c = j / 3;
      float zcv = Zc[zuid * 12 + j];
      float r = resc[zuid * 4 + c];
      oo[k] = zcv + (zz[k] - zcv) * r;
    }
    f4 ov = {oo[0], oo[1], oo[2], oo[3]};
    ((f4*)Zout)[atom * 3 + comp] = ov;
  }
}

extern "C" void kernel_launch(void* const* d_in, const int* in_sizes, int n_in,
                              void* d_out, int out_size, void* d_ws, size_t ws_size,
                              hipStream_t stream) {
  const float* H     = (const float*)d_in[0];
  const float* Z     = (const float*)d_in[1];
  const float* sigma = (const float*)d_in[2];
  const float* W1    = (const float*)d_in[3];
  const float* b1    = (const float*)d_in[4];
  const float* W2    = (const float*)d_in[5];
  const float* b2    = (const float*)d_in[6];
  const float* ln_w  = (const float*)d_in[7];
  const float* ln_b  = (const float*)d_in[8];
  const int* block_id = (const int*)d_in[9];
  const int* batch_id = (const int*)d_in[10];

  float* ws   = (float*)d_ws;
  float* acc  = ws + ACC_OFF;
  float* Zc   = ws + ZC_OFF;
  float* resc = ws + RS_OFF;
  float* hbuf = ws + HB_OFF;
  unsigned char* uid8 = (unsigned char*)(ws + UID_OFF);

  float* Hout = (float*)d_out;
  float* Zout = Hout + (size_t)N_ATOMS * DH;
  float* resc_out = Zout + (size_t)N_ATOMS * 12;

  hipMemsetAsync(acc, 0, BATCHES * 17 * sizeof(float), stream);
  k1_stats<<<(N_ATOMS + 255) / 256, 256, 0, stream>>>(Z, block_id, batch_id, acc, uid8);
  k2_mlp<<<BATCHES, 128, 0, stream>>>(sigma, W1, b1, W2, b2, acc, Zc, resc, hbuf, resc_out);
  k3_apply<<<N_ATOMS / 64, 256, 0, stream>>>(H, Z, uid8, ln_w, ln_b,
                                             Zc, resc, hbuf, Hout, Zout);
}